// Round 8
// baseline (194.405 us; speedup 1.0000x reference)
//
#include <hip/hip_runtime.h>
#include <math.h>

#define BB 64
#define HH 480
#define WW 640
#define PH 64
#define PW 512
#define FS 15
#define NF 7
#define RR 7              // FS/2
#define GD 448            // B*NF
#define KTOT 32768        // PH*PW

#define GSPL 32               // gram K splits (partial planes in ws); 896 blocks = 3.5/CU
#define KPB (KTOT / GSPL)     // 1024 K per block
#define GSTK 64               // K per LDS stage
#define GNST (KPB / GSTK)     // 16 stages
#define GPLW 68               // LDS row pitch (bf16): 136B = b64-aligned, 34 dw == 2 mod 32 -> 2-way (free)

// fallback (hi/lo, atomic) gram params
#define FSPL 32
#define FKPB (KTOT / FSPL)
#define GBK 32
#define GNB (FKPB / GBK)
#define PLW 40

// conv-MFMA params
#define CJT 32                // output j-span per block
#define CSP 52                // stage pitch in f16 (26 dwords, EVEN -> b64-aligned frag reads)
#define CSPD 26               // stage pitch in dwords
#define CSROWS 31             // 16 + 15 staged rows for one i-tile
#define CSY 46                // staged cols used (15 + 32 - 1)
#define OBP 36                // outBuf row pitch (floats): 144B (16B-aligned rows), kills o-plane bank collision

static constexpr long CODES_N = (long)BB * NF * PH * PW;   // 14,680,064
static constexpr long GRAM_N  = (long)GD * GD;             // 200,704
static constexpr long POLAR_N = (long)BB * PH * PW;        // 2,097,152
static constexpr size_t BF_BYTES   = (size_t)GD * KTOT * 2;          // 29,360,128
static constexpr size_t PART_BYTES = (size_t)GSPL * GRAM_N * 4;      // 25,690,112
static constexpr size_t WTAB_BYTES = 512 * 16;                       // 8 KB f16 table

typedef __bf16    bf16x4   __attribute__((ext_vector_type(4)));
typedef __bf16    bf16x8   __attribute__((ext_vector_type(8)));
typedef _Float16  f16x8    __attribute__((ext_vector_type(8)));
typedef float     floatx4  __attribute__((ext_vector_type(4)));
typedef float     floatx16 __attribute__((ext_vector_type(16)));

union bfu { bf16x8 v; bf16x4 h[2]; };

// upper-triangle 64x64 tile pairs (by<=bx), 7 tiles -> 28 pairs
__constant__ int c_by[28] = {0,0,0,0,0,0,0, 1,1,1,1,1,1, 2,2,2,2,2, 3,3,3,3, 4,4,4, 5,5, 6};
__constant__ int c_bx[28] = {0,1,2,3,4,5,6, 1,2,3,4,5,6, 2,3,4,5,6, 3,4,5,6, 4,5,6, 5,6, 6};

// shared helper: W fragment value for (slot s∈[0,8), lane l∈[0,64), elem e∈[0,8))
__device__ __forceinline__ float wfrag_val(const float* fm, int s, int l, int e) {
    int du = l >> 5;
    int v0 = ((l >> 4) & 1) * 8;
    int n  = l & 15;
    int jd = (n >= NF) ? 1 : 0;
    int o  = n - NF * jd;
    int u  = 2 * s + du;
    int v  = v0 + e;
    int vp = v - jd;
    float wv = 0.0f;
    if (n < 2 * NF && u < FS && vp >= 0 && vp < FS)
        wv = fm[(u * FS + vp) * NF + (NF - 1 - o)];
    return wv;
}

// ---------------------------------------------------------------- K1: polar unwarp (+ W table build by block 0)
__global__ __launch_bounds__(256) void polar_kernel(
        const float* __restrict__ img,
        const float* __restrict__ pupil,
        const float* __restrict__ iris,
        const float* __restrict__ fm,
        float* __restrict__ polar,
        _Float16* __restrict__ wtab) {
    if (wtab && blockIdx.x == 0) {
        // 512 slots, 2 per thread: wtab[slot] = f16x8 B-fragment
        #pragma unroll
        for (int ss = 0; ss < 2; ++ss) {
            int slot = threadIdx.x + ss * 256;
            int s = slot >> 6, l = slot & 63;
            f16x8 vv;
            #pragma unroll
            for (int e = 0; e < 8; ++e) vv[e] = (_Float16)wfrag_val(fm, s, l, e);
            *(f16x8*)&wtab[slot * 8] = vv;
        }
    }

    int t = blockIdx.x * 256 + threadIdx.x;
    if (t >= (int)POLAR_N) return;
    int j = t & (PW - 1);
    int i = (t >> 9) & (PH - 1);
    int b = t >> 15;

    float theta = 6.2831855f * (float)(j + 1) / (float)PW;
    float s, c;
    __sincosf(theta, &s, &c);

    float pcx = pupil[b * 3 + 0], pcy = pupil[b * 3 + 1], pr = pupil[b * 3 + 2];
    float icx = iris[b * 3 + 0],  icy = iris[b * 3 + 1],  ir = iris[b * 3 + 2];

    float px = pcx + pr * c;
    float py = pcy + pr * s;
    float ix = icx + ir * c;
    float iy = icy + ir * s;

    float r = (float)i / 63.0f;
    float xg = (1.0f - r) * px + r * ix;
    float yg = (1.0f - r) * py + r * iy;

    float x = fminf(fmaxf(xg, 0.0f), (float)(WW - 1));
    float y = fminf(fmaxf(yg, 0.0f), (float)(HH - 1));

    float xn = x / (float)(WW - 1) * 2.0f - 1.0f;
    float gx = ((xn + 1.0f) / 2.0f * (float)WW - 0.5f) / (float)(WW - 1) * 2.0f - 1.0f;
    float xs = ((gx + 1.0f) * (float)WW - 1.0f) / 2.0f;

    float yn = y / (float)(HH - 1) * 2.0f - 1.0f;
    float gy = ((yn + 1.0f) / 2.0f * (float)HH - 0.5f) / (float)(HH - 1) * 2.0f - 1.0f;
    float ys = ((gy + 1.0f) * (float)HH - 1.0f) / 2.0f;

    float x0f = floorf(xs), y0f = floorf(ys);
    float wx = xs - x0f, wy = ys - y0f;
    int x0 = (int)x0f, y0 = (int)y0f;

    const float* im = img + (size_t)b * (HH * WW);
    float v00 = 0.f, v01 = 0.f, v10 = 0.f, v11 = 0.f;
    bool xv0 = (x0 >= 0) & (x0 < WW);
    bool xv1 = (x0 + 1 >= 0) & (x0 + 1 < WW);
    bool yv0 = (y0 >= 0) & (y0 < HH);
    bool yv1 = (y0 + 1 >= 0) & (y0 + 1 < HH);
    if (xv0 & yv0) v00 = im[(size_t)y0 * WW + x0];
    if (xv1 & yv0) v01 = im[(size_t)y0 * WW + x0 + 1];
    if (xv0 & yv1) v10 = im[(size_t)(y0 + 1) * WW + x0];
    if (xv1 & yv1) v11 = im[(size_t)(y0 + 1) * WW + x0 + 1];

    float val = v00 * (1.0f - wx) * (1.0f - wy) + v01 * wx * (1.0f - wy)
              + v10 * (1.0f - wx) * wy          + v11 * wx * wy;
    polar[t] = val * 255.0f;
}

// ---------------------------------------------------------------- K2: wrap conv 15x15x7 via MFMA (f16 inputs, fp32 accum)
// v5b: v4 + non-temporal streaming stores via ext_vector types (nt builtin rejects HIP_vector_type).
__global__ __launch_bounds__(256) void conv_mfma_kernel(
        const float* __restrict__ polar,
        const float* __restrict__ fm,
        const _Float16* __restrict__ wtab,
        float* __restrict__ codes,
        __bf16* __restrict__ cbf) {
    __shared__ __align__(16) _Float16 stg[CSROWS * CSP];      // 3224 B
    __shared__ __align__(16) float outBuf[16 * NF * OBP];     // 16128 B; front 8KB aliased as Wbuf (fallback)

    int bid = blockIdx.x;
    int b   = bid >> 6;
    int jt  = (bid >> 2) & 15;
    int it  = bid & 3;
    int j0  = jt * CJT;
    int i0  = it * 16;
    int tid  = threadIdx.x;
    int lane = tid & 63;
    int w    = tid >> 6;

    const float* pb = polar + (size_t)b * (PH * PW);

    // ---- stage polar tile -> f16 LDS (row r covers polar row (i0+r-7)&63, col y -> (j0-7+y)&511)
    for (int e = tid; e < CSROWS * CSY; e += 256) {
        int r = e / CSY;
        int y = e - r * CSY;
        int grow = (i0 + r - RR) & (PH - 1);
        int gcol = (j0 - RR + y) & (PW - 1);
        stg[r * CSP + y] = (_Float16)pb[grow * PW + gcol];
    }

    // ---- W fragments -> registers
    f16x8 Wreg[8];
    if (wtab) {
        #pragma unroll
        for (int s = 0; s < 8; ++s)
            Wreg[s] = *(const f16x8*)&wtab[(s * 64 + lane) * 8];
        __syncthreads();
    } else {
        // fallback: build in LDS (aliased into outBuf)
        uint4* Wb = (uint4*)outBuf;
        for (int slot = tid; slot < 512; slot += 256) {
            int s = slot >> 6, l = slot & 63;
            f16x8 vv;
            #pragma unroll
            for (int e2 = 0; e2 < 8; ++e2) vv[e2] = (_Float16)wfrag_val(fm, s, l, e2);
            Wb[slot] = *(const uint4*)&vv;
        }
        __syncthreads();
        #pragma unroll
        for (int s = 0; s < 8; ++s)
            Wreg[s] = *(const f16x8*)&Wb[s * 64 + lane];
        __syncthreads();
    }

    const unsigned int* stg32 = (const unsigned int*)stg;
    int mrow = lane & 15;
    int du   = lane >> 5;
    int v0h  = ((lane >> 4) & 1) * 4;   // v0/2 in dwords
    int n    = lane & 15;
    int jd   = (n >= NF) ? 1 : 0;
    int o    = n - NF * jd;
    int g4   = lane >> 4;

    floatx4 acc0 = {}, acc1 = {}, acc2 = {}, acc3 = {};
    #pragma unroll
    for (int s = 0; s < 8; ++s) {
        // wave-shared span: dwords [dbase .. dbase+7], dbase always EVEN (26r+4w+v0h)
        int dbase = CSPD * (mrow + du + 2 * s) + 4 * w + v0h;
        uint2 u01 = *(const uint2*)&stg32[dbase + 0];
        uint2 u23 = *(const uint2*)&stg32[dbase + 2];
        uint2 u45 = *(const uint2*)&stg32[dbase + 4];
        uint2 u67 = *(const uint2*)&stg32[dbase + 6];
        unsigned int ud0 = u01.x, ud1 = u01.y, ud2 = u23.x, ud3 = u23.y;
        unsigned int ud4 = u45.x, ud5 = u45.y, ud6 = u67.x, ud7 = u67.y;
        uint4 a0 = make_uint4(ud0, ud1, ud2, ud3);
        uint4 a1 = make_uint4(ud1, ud2, ud3, ud4);
        uint4 a2 = make_uint4(ud2, ud3, ud4, ud5);
        uint4 a3 = make_uint4(ud3, ud4, ud5, ud6);
        (void)ud7;
        acc0 = __builtin_amdgcn_mfma_f32_16x16x32_f16(*(const f16x8*)&a0, Wreg[s], acc0, 0, 0, 0);
        acc1 = __builtin_amdgcn_mfma_f32_16x16x32_f16(*(const f16x8*)&a1, Wreg[s], acc1, 0, 0, 0);
        acc2 = __builtin_amdgcn_mfma_f32_16x16x32_f16(*(const f16x8*)&a2, Wreg[s], acc2, 0, 0, 0);
        acc3 = __builtin_amdgcn_mfma_f32_16x16x32_f16(*(const f16x8*)&a3, Wreg[s], acc3, 0, 0, 0);
    }
    if (n < 2 * NF) {
        #pragma unroll
        for (int r = 0; r < 4; ++r) {
            int il = 4 * g4 + r;
            int orow = (il * NF + o) * OBP;
            outBuf[orow + 2 * (w * 4 + 0) + jd] = acc0[r];
            outBuf[orow + 2 * (w * 4 + 1) + jd] = acc1[r];
            outBuf[orow + 2 * (w * 4 + 2) + jd] = acc2[r];
            outBuf[orow + 2 * (w * 4 + 3) + jd] = acc3[r];
        }
    }
    __syncthreads();
    // ---- coalesced streaming store: outBuf[il][o][j] -> codes / cbf
    for (int g = tid; g < NF * 16 * (CJT / 4); g += 256) {   // 896 float4 groups
        int oo  = g >> 7;
        int rem = g & 127;
        int il  = rem >> 3;
        int j4  = rem & 7;
        floatx4 v = *(const floatx4*)&outBuf[(il * NF + oo) * OBP + j4 * 4];
        size_t gbase = (((size_t)b * NF + oo) * PH + i0 + il) * PW + j0 + j4 * 4;
        __builtin_nontemporal_store(v, (floatx4*)&codes[gbase]);
        if (cbf) {
            bf16x4 bv;
            bv[0] = (__bf16)v.x; bv[1] = (__bf16)v.y;
            bv[2] = (__bf16)v.z; bv[3] = (__bf16)v.w;
            __builtin_nontemporal_store(bv, (bf16x4*)&cbf[gbase]);
        }
    }
}

// ---------------------------------------------------------------- K3: gram, bf16 MFMA SYRK -> partial planes (no atomics)
// v5: GSPL=32 (896 blocks = 3.5/CU, 14 waves/CU). ky = bid & 31 -> XCD = bid % 8 sees
// ky ≡ {k, k+8, k+16, k+24}: per-XCD feats working set 4 x 0.875 MB = 3.5 MB < 4 MB L2.
__global__ __launch_bounds__(256) void gram_bf_kernel(
        const __bf16* __restrict__ feats,
        float* __restrict__ partials) {
    __shared__ __bf16 Ab[2][64][GPLW];
    __shared__ __bf16 Bb[2][64][GPLW];

    int bid = blockIdx.x;
    int pi  = bid >> 5;               // 0..27 tile pair
    int ky  = bid & 31;               // 0..31 K slice (low bits -> XCD locality)
    int by = c_by[pi], bx = c_bx[pi];
    int p0 = by * 64, q0 = bx * 64;
    size_t kbase = (size_t)ky * KPB;

    int tid = threadIdx.x;
    int lane = tid & 63;
    int w = tid >> 6;
    int wr = w >> 1, wc = w & 1;        // 2x2 waves over 64x64 tile

    int srow = tid >> 3;                // 0..31
    int slot = tid & 7;                 // k-octet
    const __bf16* apA  = feats + (size_t)(p0 + srow) * KTOT + kbase + slot * 8;
    const __bf16* apA2 = apA + (size_t)32 * KTOT;
    const __bf16* apB  = feats + (size_t)(q0 + srow) * KTOT + kbase + slot * 8;
    const __bf16* apB2 = apB + (size_t)32 * KTOT;

    int arow = 32 * wr + (lane & 31);
    int brow = 32 * wc + (lane & 31);
    int ko = (lane >> 5) * 8;

    floatx16 acc = {};

    bfu ra0, ra1, rb0, rb1, na0, na1, nb0, nb1;
    ra0.v = *(const bf16x8*)(apA);
    ra1.v = *(const bf16x8*)(apA2);
    rb0.v = *(const bf16x8*)(apB);
    rb1.v = *(const bf16x8*)(apB2);
    na0.v = *(const bf16x8*)(apA + GSTK);
    na1.v = *(const bf16x8*)(apA2 + GSTK);
    nb0.v = *(const bf16x8*)(apB + GSTK);
    nb1.v = *(const bf16x8*)(apB2 + GSTK);

    for (int s = 0; s < GNST; ++s) {
        int p = s & 1;
        *(bf16x4*)&Ab[p][srow][slot * 8]          = ra0.h[0];
        *(bf16x4*)&Ab[p][srow][slot * 8 + 4]      = ra0.h[1];
        *(bf16x4*)&Ab[p][srow + 32][slot * 8]     = ra1.h[0];
        *(bf16x4*)&Ab[p][srow + 32][slot * 8 + 4] = ra1.h[1];
        *(bf16x4*)&Bb[p][srow][slot * 8]          = rb0.h[0];
        *(bf16x4*)&Bb[p][srow][slot * 8 + 4]      = rb0.h[1];
        *(bf16x4*)&Bb[p][srow + 32][slot * 8]     = rb1.h[0];
        *(bf16x4*)&Bb[p][srow + 32][slot * 8 + 4] = rb1.h[1];
        __syncthreads();
        ra0 = na0; ra1 = na1; rb0 = nb0; rb1 = nb1;
        if (s + 2 < GNST) {
            size_t off = (size_t)(s + 2) * GSTK;
            na0.v = *(const bf16x8*)(apA + off);
            na1.v = *(const bf16x8*)(apA2 + off);
            nb0.v = *(const bf16x8*)(apB + off);
            nb1.v = *(const bf16x8*)(apB2 + off);
        }
        #pragma unroll
        for (int st = 0; st < 4; ++st) {
            bfu af, bg;
            af.h[0] = *(const bf16x4*)&Ab[p][arow][st * 16 + ko];
            af.h[1] = *(const bf16x4*)&Ab[p][arow][st * 16 + ko + 4];
            bg.h[0] = *(const bf16x4*)&Bb[p][brow][st * 16 + ko];
            bg.h[1] = *(const bf16x4*)&Bb[p][brow][st * 16 + ko + 4];
            acc = __builtin_amdgcn_mfma_f32_32x32x16_bf16(af.v, bg.v, acc, 0, 0, 0);
        }
    }

    float* part = partials + (size_t)ky * GRAM_N;
    int col = lane & 31;
    #pragma unroll
    for (int r = 0; r < 16; ++r) {
        int row = (r & 3) + 8 * (r >> 2) + 4 * (lane >> 5);
        int p = p0 + 32 * wr + row;
        int q = q0 + 32 * wc + col;
        float v = acc[r];
        part[(size_t)p * GD + q] = v;
        if (bx != by) part[(size_t)q * GD + p] = v;
    }
}

// ---------------------------------------------------------------- K4: reduce partials -> gram
__global__ __launch_bounds__(256) void gram_reduce_kernel(
        const float* __restrict__ partials,
        float* __restrict__ gram) {
    int t = blockIdx.x * 256 + threadIdx.x;   // 50176 float4 groups
    const float scale = 1.0f / 14680064.0f;
    float4 s = make_float4(0.f, 0.f, 0.f, 0.f);
    #pragma unroll
    for (int sp = 0; sp < GSPL; ++sp) {
        float4 v = *(const float4*)&partials[(size_t)sp * GRAM_N + (size_t)t * 4];
        s.x += v.x; s.y += v.y; s.z += v.z; s.w += v.w;
    }
    s.x *= scale; s.y *= scale; s.z *= scale; s.w *= scale;
    *(float4*)&gram[(size_t)t * 4] = s;
}

// ---------------------------------------------------------------- K3 fallback: hi/lo split, atomics (no ws needed)
__device__ __forceinline__ void split4(float4 v, bf16x4& h, bf16x4& l) {
    float x[4] = {v.x, v.y, v.z, v.w};
    #pragma unroll
    for (int j = 0; j < 4; ++j) {
        __bf16 hh = (__bf16)x[j];
        h[j] = hh;
        l[j] = (__bf16)(x[j] - (float)hh);
    }
}

__global__ __launch_bounds__(256) void gram_hilo_kernel(
        const float* __restrict__ feats,
        float* __restrict__ gram) {
    __shared__ __bf16 Ah[2][64][PLW], Al[2][64][PLW];
    __shared__ __bf16 Bh[2][64][PLW], Bl[2][64][PLW];

    int pi = blockIdx.x;
    int by = c_by[pi], bx = c_bx[pi];
    int p0 = by * 64, q0 = bx * 64;
    int kbase = blockIdx.y * FKPB;

    int tid = threadIdx.x;
    int lane = tid & 63;
    int w = tid >> 6;
    int wr = w >> 1, wc = w & 1;

    int r0 = tid >> 3;
    int slot = tid & 7;
    const float* ap0 = feats + (size_t)(p0 + r0)      * KTOT + kbase + slot * 4;
    const float* ap1 = feats + (size_t)(p0 + r0 + 32) * KTOT + kbase + slot * 4;
    const float* bp0 = feats + (size_t)(q0 + r0)      * KTOT + kbase + slot * 4;
    const float* bp1 = feats + (size_t)(q0 + r0 + 32) * KTOT + kbase + slot * 4;

    int frow = lane & 31;
    int arow = 32 * wr + frow;
    int brow = 32 * wc + frow;
    int kq = (lane >> 5) * 8;

    floatx16 acc = {};

    {
        float4 a0 = *(const float4*)ap0;
        float4 a1 = *(const float4*)ap1;
        float4 b0 = *(const float4*)bp0;
        float4 b1 = *(const float4*)bp1;
        bf16x4 h, l;
        split4(a0, h, l); *(bf16x4*)&Ah[0][r0][slot*4] = h;      *(bf16x4*)&Al[0][r0][slot*4] = l;
        split4(a1, h, l); *(bf16x4*)&Ah[0][r0+32][slot*4] = h;   *(bf16x4*)&Al[0][r0+32][slot*4] = l;
        split4(b0, h, l); *(bf16x4*)&Bh[0][r0][slot*4] = h;      *(bf16x4*)&Bl[0][r0][slot*4] = l;
        split4(b1, h, l); *(bf16x4*)&Bh[0][r0+32][slot*4] = h;   *(bf16x4*)&Bl[0][r0+32][slot*4] = l;
    }
    __syncthreads();

    for (int s = 0; s < GNB; ++s) {
        int buf = s & 1;
        float4 a0, a1, b0, b1;
        if (s + 1 < GNB) {
            int off = (s + 1) * GBK;
            a0 = *(const float4*)(ap0 + off);
            a1 = *(const float4*)(ap1 + off);
            b0 = *(const float4*)(bp0 + off);
            b1 = *(const float4*)(bp1 + off);
        }
        #pragma unroll
        for (int kk = 0; kk < 2; ++kk) {
            int ko = kq + kk * 16;
            bf16x8 ah = *(const bf16x8*)&Ah[buf][arow][ko];
            bf16x8 al = *(const bf16x8*)&Al[buf][arow][ko];
            bf16x8 bh = *(const bf16x8*)&Bh[buf][brow][ko];
            bf16x8 bl = *(const bf16x8*)&Bl[buf][brow][ko];
            acc = __builtin_amdgcn_mfma_f32_32x32x16_bf16(ah, bh, acc, 0, 0, 0);
            acc = __builtin_amdgcn_mfma_f32_32x32x16_bf16(ah, bl, acc, 0, 0, 0);
            acc = __builtin_amdgcn_mfma_f32_32x32x16_bf16(al, bh, acc, 0, 0, 0);
        }
        if (s + 1 < GNB) {
            int nb = (s + 1) & 1;
            bf16x4 h, l;
            split4(a0, h, l); *(bf16x4*)&Ah[nb][r0][slot*4] = h;      *(bf16x4*)&Al[nb][r0][slot*4] = l;
            split4(a1, h, l); *(bf16x4*)&Ah[nb][r0+32][slot*4] = h;   *(bf16x4*)&Al[nb][r0+32][slot*4] = l;
            split4(b0, h, l); *(bf16x4*)&Bh[nb][r0][slot*4] = h;      *(bf16x4*)&Bl[nb][r0][slot*4] = l;
            split4(b1, h, l); *(bf16x4*)&Bh[nb][r0+32][slot*4] = h;   *(bf16x4*)&Bl[nb][r0+32][slot*4] = l;
        }
        __syncthreads();
    }

    const float scale = 1.0f / 14680064.0f;
    int col = lane & 31;
    #pragma unroll
    for (int r = 0; r < 16; ++r) {
        int row = (r & 3) + 8 * (r >> 2) + 4 * (lane >> 5);
        int p = p0 + 32 * wr + row;
        int q = q0 + 32 * wc + col;
        float v = acc[r] * scale;
        atomicAdd(&gram[(size_t)p * GD + q], v);
        if (bx != by) atomicAdd(&gram[(size_t)q * GD + p], v);
    }
}

// ---------------------------------------------------------------- launch
extern "C" void kernel_launch(void* const* d_in, const int* in_sizes, int n_in,
                              void* d_out, int out_size, void* d_ws, size_t ws_size,
                              hipStream_t stream) {
    const float* img   = (const float*)d_in[0];
    const float* pupil = (const float*)d_in[1];
    const float* iris  = (const float*)d_in[2];
    const float* fm    = (const float*)d_in[3];

    float* codes = (float*)d_out;
    float* gram  = codes + CODES_N;
    float* polar = gram + GRAM_N;

    bool use_bf = (ws_size >= BF_BYTES + PART_BYTES + WTAB_BYTES);
    __bf16* cbf = use_bf ? (__bf16*)d_ws : nullptr;
    float* partials = (float*)((char*)d_ws + BF_BYTES);
    _Float16* wtab = use_bf ? (_Float16*)((char*)d_ws + BF_BYTES + PART_BYTES) : nullptr;

    polar_kernel<<<(int)(POLAR_N / 256), 256, 0, stream>>>(img, pupil, iris, fm, polar, wtab);

    conv_mfma_kernel<<<BB * 16 * 4, 256, 0, stream>>>(polar, fm, wtab, codes, cbf);

    if (use_bf) {
        gram_bf_kernel<<<28 * GSPL, 256, 0, stream>>>((const __bf16*)d_ws, partials);
        gram_reduce_kernel<<<(int)(GRAM_N / 4 / 256), 256, 0, stream>>>(partials, gram);
    } else {
        (void)hipMemsetAsync(gram, 0, GRAM_N * sizeof(float), stream);
        dim3 ggrid(28, FSPL);
        gram_hilo_kernel<<<ggrid, 256, 0, stream>>>(codes, gram);
    }
}

// Round 9
// 187.573 us; speedup vs baseline: 1.0364x; 1.0364x over previous
//
#include <hip/hip_runtime.h>
#include <math.h>

#define BB 64
#define HH 480
#define WW 640
#define PH 64
#define PW 512
#define FS 15
#define NF 7
#define RR 7              // FS/2
#define GD 448            // B*NF
#define KTOT 32768        // PH*PW

#define GSPL 16               // gram K splits (partial planes in ws)
#define KPB (KTOT / GSPL)     // 2048 K per block
#define GSTK 64               // K per LDS stage
#define GNST (KPB / GSTK)     // 32 stages
#define GPLW 68               // LDS row pitch (bf16): 136B = b64-aligned, 34 dw == 2 mod 32 -> 2-way (free)

// fallback (hi/lo, atomic) gram params
#define FSPL 32
#define FKPB (KTOT / FSPL)
#define GBK 32
#define GNB (FKPB / GBK)
#define PLW 40

// conv-MFMA params
#define CJT 32                // output j-span per block
#define CSP 52                // stage pitch in f16 (26 dwords, EVEN -> b64-aligned frag reads)
#define CSPD 26               // stage pitch in dwords
#define CSROWS 31             // 16 + 15 staged rows for one i-tile
#define CSY 46                // staged cols used (15 + 32 - 1)
#define OBP 36                // outBuf row pitch (floats): 144B (16B-aligned rows), kills o-plane bank collision

static constexpr long CODES_N = (long)BB * NF * PH * PW;   // 14,680,064
static constexpr long GRAM_N  = (long)GD * GD;             // 200,704
static constexpr long POLAR_N = (long)BB * PH * PW;        // 2,097,152
static constexpr size_t BF_BYTES   = (size_t)GD * KTOT * 2;          // 29,360,128
static constexpr size_t PART_BYTES = (size_t)GSPL * GRAM_N * 4;      // 12,845,056
static constexpr size_t WTAB_BYTES = 512 * 16;                       // 8 KB f16 table

typedef __bf16    bf16x4   __attribute__((ext_vector_type(4)));
typedef __bf16    bf16x8   __attribute__((ext_vector_type(8)));
typedef _Float16  f16x8    __attribute__((ext_vector_type(8)));
typedef float     floatx4  __attribute__((ext_vector_type(4)));
typedef float     floatx16 __attribute__((ext_vector_type(16)));

union bfu { bf16x8 v; bf16x4 h[2]; };

// upper-triangle 64x64 tile pairs (by<=bx), 7 tiles -> 28 pairs
__constant__ int c_by[28] = {0,0,0,0,0,0,0, 1,1,1,1,1,1, 2,2,2,2,2, 3,3,3,3, 4,4,4, 5,5, 6};
__constant__ int c_bx[28] = {0,1,2,3,4,5,6, 1,2,3,4,5,6, 2,3,4,5,6, 3,4,5,6, 4,5,6, 5,6, 6};

// shared helper: W fragment value for (slot s∈[0,8), lane l∈[0,64), elem e∈[0,8))
__device__ __forceinline__ float wfrag_val(const float* fm, int s, int l, int e) {
    int du = l >> 5;
    int v0 = ((l >> 4) & 1) * 8;
    int n  = l & 15;
    int jd = (n >= NF) ? 1 : 0;
    int o  = n - NF * jd;
    int u  = 2 * s + du;
    int v  = v0 + e;
    int vp = v - jd;
    float wv = 0.0f;
    if (n < 2 * NF && u < FS && vp >= 0 && vp < FS)
        wv = fm[(u * FS + vp) * NF + (NF - 1 - o)];
    return wv;
}

// ---------------------------------------------------------------- K1: polar unwarp (+ W table build by block 0)
__global__ __launch_bounds__(256) void polar_kernel(
        const float* __restrict__ img,
        const float* __restrict__ pupil,
        const float* __restrict__ iris,
        const float* __restrict__ fm,
        float* __restrict__ polar,
        _Float16* __restrict__ wtab) {
    if (wtab && blockIdx.x == 0) {
        // 512 slots, 2 per thread: wtab[slot] = f16x8 B-fragment
        #pragma unroll
        for (int ss = 0; ss < 2; ++ss) {
            int slot = threadIdx.x + ss * 256;
            int s = slot >> 6, l = slot & 63;
            f16x8 vv;
            #pragma unroll
            for (int e = 0; e < 8; ++e) vv[e] = (_Float16)wfrag_val(fm, s, l, e);
            *(f16x8*)&wtab[slot * 8] = vv;
        }
    }

    int t = blockIdx.x * 256 + threadIdx.x;
    if (t >= (int)POLAR_N) return;
    int j = t & (PW - 1);
    int i = (t >> 9) & (PH - 1);
    int b = t >> 15;

    float theta = 6.2831855f * (float)(j + 1) / (float)PW;
    float s, c;
    __sincosf(theta, &s, &c);

    float pcx = pupil[b * 3 + 0], pcy = pupil[b * 3 + 1], pr = pupil[b * 3 + 2];
    float icx = iris[b * 3 + 0],  icy = iris[b * 3 + 1],  ir = iris[b * 3 + 2];

    float px = pcx + pr * c;
    float py = pcy + pr * s;
    float ix = icx + ir * c;
    float iy = icy + ir * s;

    float r = (float)i / 63.0f;
    float xg = (1.0f - r) * px + r * ix;
    float yg = (1.0f - r) * py + r * iy;

    float x = fminf(fmaxf(xg, 0.0f), (float)(WW - 1));
    float y = fminf(fmaxf(yg, 0.0f), (float)(HH - 1));

    float xn = x / (float)(WW - 1) * 2.0f - 1.0f;
    float gx = ((xn + 1.0f) / 2.0f * (float)WW - 0.5f) / (float)(WW - 1) * 2.0f - 1.0f;
    float xs = ((gx + 1.0f) * (float)WW - 1.0f) / 2.0f;

    float yn = y / (float)(HH - 1) * 2.0f - 1.0f;
    float gy = ((yn + 1.0f) / 2.0f * (float)HH - 0.5f) / (float)(HH - 1) * 2.0f - 1.0f;
    float ys = ((gy + 1.0f) * (float)HH - 1.0f) / 2.0f;

    float x0f = floorf(xs), y0f = floorf(ys);
    float wx = xs - x0f, wy = ys - y0f;
    int x0 = (int)x0f, y0 = (int)y0f;

    const float* im = img + (size_t)b * (HH * WW);
    float v00 = 0.f, v01 = 0.f, v10 = 0.f, v11 = 0.f;
    bool xv0 = (x0 >= 0) & (x0 < WW);
    bool xv1 = (x0 + 1 >= 0) & (x0 + 1 < WW);
    bool yv0 = (y0 >= 0) & (y0 < HH);
    bool yv1 = (y0 + 1 >= 0) & (y0 + 1 < HH);
    if (xv0 & yv0) v00 = im[(size_t)y0 * WW + x0];
    if (xv1 & yv0) v01 = im[(size_t)y0 * WW + x0 + 1];
    if (xv0 & yv1) v10 = im[(size_t)(y0 + 1) * WW + x0];
    if (xv1 & yv1) v11 = im[(size_t)(y0 + 1) * WW + x0 + 1];

    float val = v00 * (1.0f - wx) * (1.0f - wy) + v01 * wx * (1.0f - wy)
              + v10 * (1.0f - wx) * wy          + v11 * wx * wy;
    polar[t] = val * 255.0f;
}

// ---------------------------------------------------------------- K2: wrap conv 15x15x7 via MFMA (f16 inputs, fp32 accum)
// v4: one 16-row i-tile per block (4096 blocks, 2 barriers), W fragments from global table,
// outBuf pitch 36 il-major -> epilogue store conflicts <=4-way.
__global__ __launch_bounds__(256) void conv_mfma_kernel(
        const float* __restrict__ polar,
        const float* __restrict__ fm,
        const _Float16* __restrict__ wtab,
        float* __restrict__ codes,
        __bf16* __restrict__ cbf) {
    __shared__ __align__(16) _Float16 stg[CSROWS * CSP];      // 3224 B
    __shared__ __align__(16) float outBuf[16 * NF * OBP];     // 16128 B; front 8KB aliased as Wbuf (fallback)

    int bid = blockIdx.x;
    int b   = bid >> 6;
    int jt  = (bid >> 2) & 15;
    int it  = bid & 3;
    int j0  = jt * CJT;
    int i0  = it * 16;
    int tid  = threadIdx.x;
    int lane = tid & 63;
    int w    = tid >> 6;

    const float* pb = polar + (size_t)b * (PH * PW);

    // ---- stage polar tile -> f16 LDS (row r covers polar row (i0+r-7)&63, col y -> (j0-7+y)&511)
    for (int e = tid; e < CSROWS * CSY; e += 256) {
        int r = e / CSY;
        int y = e - r * CSY;
        int grow = (i0 + r - RR) & (PH - 1);
        int gcol = (j0 - RR + y) & (PW - 1);
        stg[r * CSP + y] = (_Float16)pb[grow * PW + gcol];
    }

    // ---- W fragments -> registers
    f16x8 Wreg[8];
    if (wtab) {
        #pragma unroll
        for (int s = 0; s < 8; ++s)
            Wreg[s] = *(const f16x8*)&wtab[(s * 64 + lane) * 8];
        __syncthreads();
    } else {
        // fallback: build in LDS (aliased into outBuf)
        uint4* Wb = (uint4*)outBuf;
        for (int slot = tid; slot < 512; slot += 256) {
            int s = slot >> 6, l = slot & 63;
            f16x8 vv;
            #pragma unroll
            for (int e2 = 0; e2 < 8; ++e2) vv[e2] = (_Float16)wfrag_val(fm, s, l, e2);
            Wb[slot] = *(const uint4*)&vv;
        }
        __syncthreads();
        #pragma unroll
        for (int s = 0; s < 8; ++s)
            Wreg[s] = *(const f16x8*)&Wb[s * 64 + lane];
        __syncthreads();
    }

    const unsigned int* stg32 = (const unsigned int*)stg;
    int mrow = lane & 15;
    int du   = lane >> 5;
    int v0h  = ((lane >> 4) & 1) * 4;   // v0/2 in dwords
    int n    = lane & 15;
    int jd   = (n >= NF) ? 1 : 0;
    int o    = n - NF * jd;
    int g4   = lane >> 4;

    floatx4 acc0 = {}, acc1 = {}, acc2 = {}, acc3 = {};
    #pragma unroll
    for (int s = 0; s < 8; ++s) {
        // wave-shared span: dwords [dbase .. dbase+7], dbase always EVEN (26r+4w+v0h)
        int dbase = CSPD * (mrow + du + 2 * s) + 4 * w + v0h;
        uint2 u01 = *(const uint2*)&stg32[dbase + 0];
        uint2 u23 = *(const uint2*)&stg32[dbase + 2];
        uint2 u45 = *(const uint2*)&stg32[dbase + 4];
        uint2 u67 = *(const uint2*)&stg32[dbase + 6];
        unsigned int ud0 = u01.x, ud1 = u01.y, ud2 = u23.x, ud3 = u23.y;
        unsigned int ud4 = u45.x, ud5 = u45.y, ud6 = u67.x, ud7 = u67.y;
        uint4 a0 = make_uint4(ud0, ud1, ud2, ud3);
        uint4 a1 = make_uint4(ud1, ud2, ud3, ud4);
        uint4 a2 = make_uint4(ud2, ud3, ud4, ud5);
        uint4 a3 = make_uint4(ud3, ud4, ud5, ud6);
        (void)ud7;
        acc0 = __builtin_amdgcn_mfma_f32_16x16x32_f16(*(const f16x8*)&a0, Wreg[s], acc0, 0, 0, 0);
        acc1 = __builtin_amdgcn_mfma_f32_16x16x32_f16(*(const f16x8*)&a1, Wreg[s], acc1, 0, 0, 0);
        acc2 = __builtin_amdgcn_mfma_f32_16x16x32_f16(*(const f16x8*)&a2, Wreg[s], acc2, 0, 0, 0);
        acc3 = __builtin_amdgcn_mfma_f32_16x16x32_f16(*(const f16x8*)&a3, Wreg[s], acc3, 0, 0, 0);
    }
    if (n < 2 * NF) {
        #pragma unroll
        for (int r = 0; r < 4; ++r) {
            int il = 4 * g4 + r;
            int orow = (il * NF + o) * OBP;
            outBuf[orow + 2 * (w * 4 + 0) + jd] = acc0[r];
            outBuf[orow + 2 * (w * 4 + 1) + jd] = acc1[r];
            outBuf[orow + 2 * (w * 4 + 2) + jd] = acc2[r];
            outBuf[orow + 2 * (w * 4 + 3) + jd] = acc3[r];
        }
    }
    __syncthreads();
    // ---- coalesced store: outBuf[il][o][j] -> codes / cbf
    for (int g = tid; g < NF * 16 * (CJT / 4); g += 256) {   // 896 float4 groups
        int oo  = g >> 7;
        int rem = g & 127;
        int il  = rem >> 3;
        int j4  = rem & 7;
        float4 v = *(const float4*)&outBuf[(il * NF + oo) * OBP + j4 * 4];
        size_t gbase = (((size_t)b * NF + oo) * PH + i0 + il) * PW + j0 + j4 * 4;
        *(float4*)&codes[gbase] = v;
        if (cbf) {
            bf16x4 bv;
            bv[0] = (__bf16)v.x; bv[1] = (__bf16)v.y;
            bv[2] = (__bf16)v.z; bv[3] = (__bf16)v.w;
            *(bf16x4*)&cbf[gbase] = bv;
        }
    }
}

// ---------------------------------------------------------------- K3: gram, bf16 MFMA SYRK -> partial planes (no atomics)
// v4: 1D grid 448, ky = bid & 15 -> XCD = bid % 8 sees only ky ∈ {k, k+8}:
// per-XCD L2 working set 2 x 1.75 MB = 3.5 MB < 4 MB -> each feats byte fetched once.
__global__ __launch_bounds__(256) void gram_bf_kernel(
        const __bf16* __restrict__ feats,
        float* __restrict__ partials) {
    __shared__ __bf16 Ab[2][64][GPLW];
    __shared__ __bf16 Bb[2][64][GPLW];

    int bid = blockIdx.x;
    int pi  = bid >> 4;               // 0..27 tile pair
    int ky  = bid & 15;               // 0..15 K slice (low bits -> XCD locality)
    int by = c_by[pi], bx = c_bx[pi];
    int p0 = by * 64, q0 = bx * 64;
    size_t kbase = (size_t)ky * KPB;

    int tid = threadIdx.x;
    int lane = tid & 63;
    int w = tid >> 6;
    int wr = w >> 1, wc = w & 1;        // 2x2 waves over 64x64 tile

    int srow = tid >> 3;                // 0..31
    int slot = tid & 7;                 // k-octet
    const __bf16* apA  = feats + (size_t)(p0 + srow) * KTOT + kbase + slot * 8;
    const __bf16* apA2 = apA + (size_t)32 * KTOT;
    const __bf16* apB  = feats + (size_t)(q0 + srow) * KTOT + kbase + slot * 8;
    const __bf16* apB2 = apB + (size_t)32 * KTOT;

    int arow = 32 * wr + (lane & 31);
    int brow = 32 * wc + (lane & 31);
    int ko = (lane >> 5) * 8;

    floatx16 acc = {};

    bfu ra0, ra1, rb0, rb1, na0, na1, nb0, nb1;
    ra0.v = *(const bf16x8*)(apA);
    ra1.v = *(const bf16x8*)(apA2);
    rb0.v = *(const bf16x8*)(apB);
    rb1.v = *(const bf16x8*)(apB2);
    na0.v = *(const bf16x8*)(apA + GSTK);
    na1.v = *(const bf16x8*)(apA2 + GSTK);
    nb0.v = *(const bf16x8*)(apB + GSTK);
    nb1.v = *(const bf16x8*)(apB2 + GSTK);

    for (int s = 0; s < GNST; ++s) {
        int p = s & 1;
        *(bf16x4*)&Ab[p][srow][slot * 8]          = ra0.h[0];
        *(bf16x4*)&Ab[p][srow][slot * 8 + 4]      = ra0.h[1];
        *(bf16x4*)&Ab[p][srow + 32][slot * 8]     = ra1.h[0];
        *(bf16x4*)&Ab[p][srow + 32][slot * 8 + 4] = ra1.h[1];
        *(bf16x4*)&Bb[p][srow][slot * 8]          = rb0.h[0];
        *(bf16x4*)&Bb[p][srow][slot * 8 + 4]      = rb0.h[1];
        *(bf16x4*)&Bb[p][srow + 32][slot * 8]     = rb1.h[0];
        *(bf16x4*)&Bb[p][srow + 32][slot * 8 + 4] = rb1.h[1];
        __syncthreads();
        ra0 = na0; ra1 = na1; rb0 = nb0; rb1 = nb1;
        if (s + 2 < GNST) {
            size_t off = (size_t)(s + 2) * GSTK;
            na0.v = *(const bf16x8*)(apA + off);
            na1.v = *(const bf16x8*)(apA2 + off);
            nb0.v = *(const bf16x8*)(apB + off);
            nb1.v = *(const bf16x8*)(apB2 + off);
        }
        #pragma unroll
        for (int st = 0; st < 4; ++st) {
            bfu af, bg;
            af.h[0] = *(const bf16x4*)&Ab[p][arow][st * 16 + ko];
            af.h[1] = *(const bf16x4*)&Ab[p][arow][st * 16 + ko + 4];
            bg.h[0] = *(const bf16x4*)&Bb[p][brow][st * 16 + ko];
            bg.h[1] = *(const bf16x4*)&Bb[p][brow][st * 16 + ko + 4];
            acc = __builtin_amdgcn_mfma_f32_32x32x16_bf16(af.v, bg.v, acc, 0, 0, 0);
        }
    }

    float* part = partials + (size_t)ky * GRAM_N;
    int col = lane & 31;
    #pragma unroll
    for (int r = 0; r < 16; ++r) {
        int row = (r & 3) + 8 * (r >> 2) + 4 * (lane >> 5);
        int p = p0 + 32 * wr + row;
        int q = q0 + 32 * wc + col;
        float v = acc[r];
        part[(size_t)p * GD + q] = v;
        if (bx != by) part[(size_t)q * GD + p] = v;
    }
}

// ---------------------------------------------------------------- K4: reduce partials -> gram
__global__ __launch_bounds__(256) void gram_reduce_kernel(
        const float* __restrict__ partials,
        float* __restrict__ gram) {
    int t = blockIdx.x * 256 + threadIdx.x;   // 50176 float4 groups
    const float scale = 1.0f / 14680064.0f;
    float4 s = make_float4(0.f, 0.f, 0.f, 0.f);
    #pragma unroll
    for (int sp = 0; sp < GSPL; ++sp) {
        float4 v = *(const float4*)&partials[(size_t)sp * GRAM_N + (size_t)t * 4];
        s.x += v.x; s.y += v.y; s.z += v.z; s.w += v.w;
    }
    s.x *= scale; s.y *= scale; s.z *= scale; s.w *= scale;
    *(float4*)&gram[(size_t)t * 4] = s;
}

// ---------------------------------------------------------------- K3 fallback: hi/lo split, atomics (no ws needed)
__device__ __forceinline__ void split4(float4 v, bf16x4& h, bf16x4& l) {
    float x[4] = {v.x, v.y, v.z, v.w};
    #pragma unroll
    for (int j = 0; j < 4; ++j) {
        __bf16 hh = (__bf16)x[j];
        h[j] = hh;
        l[j] = (__bf16)(x[j] - (float)hh);
    }
}

__global__ __launch_bounds__(256) void gram_hilo_kernel(
        const float* __restrict__ feats,
        float* __restrict__ gram) {
    __shared__ __bf16 Ah[2][64][PLW], Al[2][64][PLW];
    __shared__ __bf16 Bh[2][64][PLW], Bl[2][64][PLW];

    int pi = blockIdx.x;
    int by = c_by[pi], bx = c_bx[pi];
    int p0 = by * 64, q0 = bx * 64;
    int kbase = blockIdx.y * FKPB;

    int tid = threadIdx.x;
    int lane = tid & 63;
    int w = tid >> 6;
    int wr = w >> 1, wc = w & 1;

    int r0 = tid >> 3;
    int slot = tid & 7;
    const float* ap0 = feats + (size_t)(p0 + r0)      * KTOT + kbase + slot * 4;
    const float* ap1 = feats + (size_t)(p0 + r0 + 32) * KTOT + kbase + slot * 4;
    const float* bp0 = feats + (size_t)(q0 + r0)      * KTOT + kbase + slot * 4;
    const float* bp1 = feats + (size_t)(q0 + r0 + 32) * KTOT + kbase + slot * 4;

    int frow = lane & 31;
    int arow = 32 * wr + frow;
    int brow = 32 * wc + frow;
    int kq = (lane >> 5) * 8;

    floatx16 acc = {};

    {
        float4 a0 = *(const float4*)ap0;
        float4 a1 = *(const float4*)ap1;
        float4 b0 = *(const float4*)bp0;
        float4 b1 = *(const float4*)bp1;
        bf16x4 h, l;
        split4(a0, h, l); *(bf16x4*)&Ah[0][r0][slot*4] = h;      *(bf16x4*)&Al[0][r0][slot*4] = l;
        split4(a1, h, l); *(bf16x4*)&Ah[0][r0+32][slot*4] = h;   *(bf16x4*)&Al[0][r0+32][slot*4] = l;
        split4(b0, h, l); *(bf16x4*)&Bh[0][r0][slot*4] = h;      *(bf16x4*)&Bl[0][r0][slot*4] = l;
        split4(b1, h, l); *(bf16x4*)&Bh[0][r0+32][slot*4] = h;   *(bf16x4*)&Bl[0][r0+32][slot*4] = l;
    }
    __syncthreads();

    for (int s = 0; s < GNB; ++s) {
        int buf = s & 1;
        float4 a0, a1, b0, b1;
        if (s + 1 < GNB) {
            int off = (s + 1) * GBK;
            a0 = *(const float4*)(ap0 + off);
            a1 = *(const float4*)(ap1 + off);
            b0 = *(const float4*)(bp0 + off);
            b1 = *(const float4*)(bp1 + off);
        }
        #pragma unroll
        for (int kk = 0; kk < 2; ++kk) {
            int ko = kq + kk * 16;
            bf16x8 ah = *(const bf16x8*)&Ah[buf][arow][ko];
            bf16x8 al = *(const bf16x8*)&Al[buf][arow][ko];
            bf16x8 bh = *(const bf16x8*)&Bh[buf][brow][ko];
            bf16x8 bl = *(const bf16x8*)&Bl[buf][brow][ko];
            acc = __builtin_amdgcn_mfma_f32_32x32x16_bf16(ah, bh, acc, 0, 0, 0);
            acc = __builtin_amdgcn_mfma_f32_32x32x16_bf16(ah, bl, acc, 0, 0, 0);
            acc = __builtin_amdgcn_mfma_f32_32x32x16_bf16(al, bh, acc, 0, 0, 0);
        }
        if (s + 1 < GNB) {
            int nb = (s + 1) & 1;
            bf16x4 h, l;
            split4(a0, h, l); *(bf16x4*)&Ah[nb][r0][slot*4] = h;      *(bf16x4*)&Al[nb][r0][slot*4] = l;
            split4(a1, h, l); *(bf16x4*)&Ah[nb][r0+32][slot*4] = h;   *(bf16x4*)&Al[nb][r0+32][slot*4] = l;
            split4(b0, h, l); *(bf16x4*)&Bh[nb][r0][slot*4] = h;      *(bf16x4*)&Bl[nb][r0][slot*4] = l;
            split4(b1, h, l); *(bf16x4*)&Bh[nb][r0+32][slot*4] = h;   *(bf16x4*)&Bl[nb][r0+32][slot*4] = l;
        }
        __syncthreads();
    }

    const float scale = 1.0f / 14680064.0f;
    int col = lane & 31;
    #pragma unroll
    for (int r = 0; r < 16; ++r) {
        int row = (r & 3) + 8 * (r >> 2) + 4 * (lane >> 5);
        int p = p0 + 32 * wr + row;
        int q = q0 + 32 * wc + col;
        float v = acc[r] * scale;
        atomicAdd(&gram[(size_t)p * GD + q], v);
        if (bx != by) atomicAdd(&gram[(size_t)q * GD + p], v);
    }
}

// ---------------------------------------------------------------- launch
extern "C" void kernel_launch(void* const* d_in, const int* in_sizes, int n_in,
                              void* d_out, int out_size, void* d_ws, size_t ws_size,
                              hipStream_t stream) {
    const float* img   = (const float*)d_in[0];
    const float* pupil = (const float*)d_in[1];
    const float* iris  = (const float*)d_in[2];
    const float* fm    = (const float*)d_in[3];

    float* codes = (float*)d_out;
    float* gram  = codes + CODES_N;
    float* polar = gram + GRAM_N;

    bool use_bf = (ws_size >= BF_BYTES + PART_BYTES + WTAB_BYTES);
    __bf16* cbf = use_bf ? (__bf16*)d_ws : nullptr;
    float* partials = (float*)((char*)d_ws + BF_BYTES);
    _Float16* wtab = use_bf ? (_Float16*)((char*)d_ws + BF_BYTES + PART_BYTES) : nullptr;

    polar_kernel<<<(int)(POLAR_N / 256), 256, 0, stream>>>(img, pupil, iris, fm, polar, wtab);

    conv_mfma_kernel<<<BB * 16 * 4, 256, 0, stream>>>(polar, fm, wtab, codes, cbf);

    if (use_bf) {
        gram_bf_kernel<<<28 * GSPL, 256, 0, stream>>>((const __bf16*)d_ws, partials);
        gram_reduce_kernel<<<(int)(GRAM_N / 4 / 256), 256, 0, stream>>>(partials, gram);
    } else {
        (void)hipMemsetAsync(gram, 0, GRAM_N * sizeof(float), stream);
        dim3 ggrid(28, FSPL);
        gram_hilo_kernel<<<ggrid, 256, 0, stream>>>(codes, gram);
    }
}